// Round 1
// baseline (508.153 us; speedup 1.0000x reference)
//
#include <hip/hip_runtime.h>

// Two chained SAME 3x3 single-channel convs, fused through LDS.
// x: [B,1,2048,2048] f32, w1,w2: [1,1,3,3] f32 -> out: [B,1,2048,2048] f32.
//
// NOTE: the two convs do NOT compose to a single 5x5 at image borders,
// because the second conv zero-pads the INTERMEDIATE y. We therefore
// compute y explicitly on a (tile+halo1) region in LDS and zero it where
// its position falls outside the image.

#define IMG_H 2048
#define IMG_W 2048
#define TILE  64

__global__ __launch_bounds__(256) void conv3x3x2_fused(
    const float* __restrict__ x,
    const float* __restrict__ w1,
    const float* __restrict__ w2,
    float* __restrict__ out,
    int B)
{
    // sx: x tile rows -2..65 (68), cols -4..67 (72, padded for 16B-aligned loads)
    // storage: sx[rel_row + 2][rel_col + 4]; row stride 72 floats = 288 B (16B mult)
    __shared__ __align__(16) float sx[68][72];
    // sy: y tile rows -1..64 (66), cols -1..64 (66, padded to 68)
    // storage: sy[rel_row + 1][rel_col + 1]; row stride 68 floats = 272 B (16B mult)
    __shared__ __align__(16) float sy[66][68];

    const int tid  = threadIdx.x;
    const int tX   = blockIdx.x;
    const int tY   = blockIdx.y;
    const int b    = blockIdx.z;
    const int row0 = tY * TILE;
    const int col0 = tX * TILE;

    float k1[9], k2[9];
#pragma unroll
    for (int i = 0; i < 9; ++i) { k1[i] = w1[i]; k2[i] = w2[i]; }

    const float* xb = x + (size_t)b * IMG_H * IMG_W;

    // ---- stage 1: global -> LDS, x tile with halo, zero-filled outside image ----
    // 68 rows x 18 float4 = 1224 vector loads, coalesced.
    for (int f = tid; f < 68 * 18; f += 256) {
        int r  = f / 18;
        int c4 = f - r * 18;
        int gr = row0 - 2 + r;
        int gc = col0 - 4 + c4 * 4;
        float4 v;
        if ((unsigned)gr < (unsigned)IMG_H && gc >= 0 && gc + 3 < IMG_W) {
            v = *(const float4*)(xb + (size_t)gr * IMG_W + gc);
        } else {
            const bool rin = (unsigned)gr < (unsigned)IMG_H;
            const float* rp = xb + (size_t)gr * IMG_W;
            v.x = (rin && (unsigned)(gc + 0) < (unsigned)IMG_W) ? rp[gc + 0] : 0.f;
            v.y = (rin && (unsigned)(gc + 1) < (unsigned)IMG_W) ? rp[gc + 1] : 0.f;
            v.z = (rin && (unsigned)(gc + 2) < (unsigned)IMG_W) ? rp[gc + 2] : 0.f;
            v.w = (rin && (unsigned)(gc + 3) < (unsigned)IMG_W) ? rp[gc + 3] : 0.f;
        }
        *(float4*)&sx[r][c4 * 4] = v;
    }
    __syncthreads();

    // ---- stage 2: y = corr3x3(x, w1) on rel rows/cols -1..64; zero outside image ----
    // 66 rows x 17 col-groups of 4 (last group: 2 valid) = 1122 groups.
    for (int g = tid; g < 66 * 17; g += 256) {
        int r  = g / 17;           // sy storage row; rel y row = r - 1
        int cg = g - r * 17;       // col group; y rel cols cg*4-1 .. cg*4+2
        float s0 = 0.f, s1 = 0.f, s2 = 0.f, s3 = 0.f;
#pragma unroll
        for (int dr = 0; dr < 3; ++dr) {
            // x rel rows (r-1)-1+dr = r-2+dr -> sx storage row r+dr
            // x rel cols needed: cg*4-2 .. cg*4+3 -> storage cols cg*4+2 .. cg*4+7
            const float* rp = &sx[r + dr][cg * 4];
            float4 a  = *(const float4*)(rp);       // storage cols cg*4   .. cg*4+3
            float4 bb = *(const float4*)(rp + 4);   // storage cols cg*4+4 .. cg*4+7
            float x0 = a.z, x1 = a.w, x2 = bb.x, x3 = bb.y, x4 = bb.z, x5 = bb.w;
            float ka = k1[dr * 3 + 0], kb = k1[dr * 3 + 1], kc = k1[dr * 3 + 2];
            s0 += ka * x0 + kb * x1 + kc * x2;
            s1 += ka * x1 + kb * x2 + kc * x3;
            s2 += ka * x2 + kb * x3 + kc * x4;
            s3 += ka * x3 + kb * x4 + kc * x5;
        }
        int yr  = row0 + r - 1;
        bool rin = (unsigned)yr < (unsigned)IMG_H;
        float vs[4] = {s0, s1, s2, s3};
        int base = cg * 4 - 1;
#pragma unroll
        for (int j = 0; j < 4; ++j) {
            int rc = base + j;                  // rel y col, -1..66
            if (rc <= 64) {
                int yc = col0 + rc;
                sy[r][rc + 1] = (rin && (unsigned)yc < (unsigned)IMG_W) ? vs[j] : 0.f;
            }
        }
    }
    __syncthreads();

    // ---- stage 3: z = corr3x3(y, w2) on the 64x64 core; coalesced float4 stores ----
    float* ob = out + (size_t)b * IMG_H * IMG_W;
    for (int g = tid; g < 64 * 16; g += 256) {   // exactly 4 iterations
        int r  = g >> 4;           // 0..63
        int cg = g & 15;           // 0..15; z rel cols cg*4 .. cg*4+3
        float s0 = 0.f, s1 = 0.f, s2 = 0.f, s3 = 0.f;
#pragma unroll
        for (int dr = 0; dr < 3; ++dr) {
            // y rel rows r-1+dr -> sy storage row r+dr
            // y rel cols needed: cg*4-1 .. cg*4+4 -> storage cols cg*4 .. cg*4+5
            const float* rp = &sy[r + dr][cg * 4];
            float4 a  = *(const float4*)(rp);       // storage cols cg*4   .. cg*4+3
            float4 bb = *(const float4*)(rp + 4);   // storage cols cg*4+4 .. cg*4+7
            float y0 = a.x, y1 = a.y, y2 = a.z, y3 = a.w, y4 = bb.x, y5 = bb.y;
            float ka = k2[dr * 3 + 0], kb = k2[dr * 3 + 1], kc = k2[dr * 3 + 2];
            s0 += ka * y0 + kb * y1 + kc * y2;
            s1 += ka * y1 + kb * y2 + kc * y3;
            s2 += ka * y2 + kb * y3 + kc * y4;
            s3 += ka * y3 + kb * y4 + kc * y5;
        }
        float4 o = make_float4(s0, s1, s2, s3);
        *(float4*)(ob + (size_t)(row0 + r) * IMG_W + col0 + cg * 4) = o;
    }
}

extern "C" void kernel_launch(void* const* d_in, const int* in_sizes, int n_in,
                              void* d_out, int out_size, void* d_ws, size_t ws_size,
                              hipStream_t stream) {
    const float* x  = (const float*)d_in[0];
    const float* w1 = (const float*)d_in[1];
    const float* w2 = (const float*)d_in[2];
    float* out = (float*)d_out;
    int B = in_sizes[0] / (IMG_H * IMG_W);
    dim3 grid(IMG_W / TILE, IMG_H / TILE, B);
    conv3x3x2_fused<<<grid, dim3(256, 1, 1), 0, stream>>>(x, w1, w2, out, B);
}

// Round 2
// 480.640 us; speedup vs baseline: 1.0572x; 1.0572x over previous
//
#include <hip/hip_runtime.h>

// Two chained SAME 3x3 single-channel convs, fused through LDS.
// x: [B,1,2048,2048] f32, w1,w2: [1,1,3,3] f32 -> out: [B,1,2048,2048] f32.
//
// The two convs do NOT compose to a single 5x5 at image borders (the second
// conv zero-pads the INTERMEDIATE y), so y is computed explicitly on a
// (tile+halo1) region in LDS, zeroed where its position is outside the image.
//
// R1 fix: stage-2 stores to sy were 4x scalar ds_write_b32 per group with a
// 16B lane stride -> 8-way bank conflicts (SQ_LDS_BANK_CONFLICT ~6.6e7, ~50%
// of all CU cycles). Replaced with one aligned, lane-contiguous ds_write_b128
// (conflict-free) and dropped the divergent rc<=64 guard (pad cols 65..67 of
// sy are never consumed into a result; image-col mask covers the real edge).

#define IMG_H 2048
#define IMG_W 2048
#define TILE  64

__global__ __launch_bounds__(256) void conv3x3x2_fused(
    const float* __restrict__ x,
    const float* __restrict__ w1,
    const float* __restrict__ w2,
    float* __restrict__ out,
    int B)
{
    // sx: x tile rows -2..65 (68), cols -4..67 (72, padded for 16B-aligned loads)
    // storage: sx[rel_row + 2][rel_col + 4]; row stride 72 floats = 288 B
    __shared__ __align__(16) float sx[68][72];
    // sy: y tile rows -1..64 (66), cols -1..66 (68); storage sy[r+1][c+1]
    // row stride 68 floats = 272 B
    __shared__ __align__(16) float sy[66][68];

    const int tid  = threadIdx.x;
    const int row0 = blockIdx.y * TILE;
    const int col0 = blockIdx.x * TILE;
    const int b    = blockIdx.z;

    float k1[9], k2[9];
#pragma unroll
    for (int i = 0; i < 9; ++i) { k1[i] = w1[i]; k2[i] = w2[i]; }

    const float* xb = x + (size_t)b * IMG_H * IMG_W;

    // ---- stage 1: global -> LDS, x tile with halo, zero-filled outside image ----
    for (int f = tid; f < 68 * 18; f += 256) {
        int r  = f / 18;
        int c4 = f - r * 18;
        int gr = row0 - 2 + r;
        int gc = col0 - 4 + c4 * 4;
        float4 v;
        if ((unsigned)gr < (unsigned)IMG_H && gc >= 0 && gc + 3 < IMG_W) {
            v = *(const float4*)(xb + (size_t)gr * IMG_W + gc);
        } else {
            const bool rin = (unsigned)gr < (unsigned)IMG_H;
            const float* rp = xb + (size_t)gr * IMG_W;
            v.x = (rin && (unsigned)(gc + 0) < (unsigned)IMG_W) ? rp[gc + 0] : 0.f;
            v.y = (rin && (unsigned)(gc + 1) < (unsigned)IMG_W) ? rp[gc + 1] : 0.f;
            v.z = (rin && (unsigned)(gc + 2) < (unsigned)IMG_W) ? rp[gc + 2] : 0.f;
            v.w = (rin && (unsigned)(gc + 3) < (unsigned)IMG_W) ? rp[gc + 3] : 0.f;
        }
        *(float4*)&sx[r][c4 * 4] = v;
    }
    __syncthreads();

    // ---- stage 2: y = corr3x3(x, w1) on rel rows -1..64, cols -1..66 ----
    // 66 rows x 17 groups of 4 cols; one aligned float4 store per group.
    for (int g = tid; g < 66 * 17; g += 256) {
        int r  = g / 17;           // sy storage row; rel y row = r - 1
        int cg = g - r * 17;       // y rel cols cg*4-1 .. cg*4+2
        float s0 = 0.f, s1 = 0.f, s2 = 0.f, s3 = 0.f;
#pragma unroll
        for (int dr = 0; dr < 3; ++dr) {
            // x rel rows r-2+dr -> sx storage row r+dr
            // x rel cols cg*4-2 .. cg*4+3 -> storage cols cg*4+2 .. cg*4+7
            const float* rp = &sx[r + dr][cg * 4];
            float4 a  = *(const float4*)(rp);
            float4 bb = *(const float4*)(rp + 4);
            float x0 = a.z, x1 = a.w, x2 = bb.x, x3 = bb.y, x4 = bb.z, x5 = bb.w;
            float ka = k1[dr * 3 + 0], kb = k1[dr * 3 + 1], kc = k1[dr * 3 + 2];
            s0 += ka * x0 + kb * x1 + kc * x2;
            s1 += ka * x1 + kb * x2 + kc * x3;
            s2 += ka * x2 + kb * x3 + kc * x4;
            s3 += ka * x3 + kb * x4 + kc * x5;
        }
        const int  yr  = row0 + r - 1;
        const bool rin = (unsigned)yr < (unsigned)IMG_H;
        const int  yc0 = col0 + cg * 4 - 1;   // image col of element 0
        float4 v;
        v.x = (rin && (unsigned)(yc0 + 0) < (unsigned)IMG_W) ? s0 : 0.f;
        v.y = (rin && (unsigned)(yc0 + 1) < (unsigned)IMG_W) ? s1 : 0.f;
        v.z = (rin && (unsigned)(yc0 + 2) < (unsigned)IMG_W) ? s2 : 0.f;
        v.w = (rin && (unsigned)(yc0 + 3) < (unsigned)IMG_W) ? s3 : 0.f;
        *(float4*)&sy[r][cg * 4] = v;         // aligned, lane-contiguous b128
    }
    __syncthreads();

    // ---- stage 3: z = corr3x3(y, w2) on the 64x64 core; coalesced float4 stores ----
    float* ob = out + (size_t)b * IMG_H * IMG_W;
    for (int g = tid; g < 64 * 16; g += 256) {   // exactly 4 iterations
        int r  = g >> 4;           // 0..63
        int cg = g & 15;           // z rel cols cg*4 .. cg*4+3
        float s0 = 0.f, s1 = 0.f, s2 = 0.f, s3 = 0.f;
#pragma unroll
        for (int dr = 0; dr < 3; ++dr) {
            // y rel rows r-1+dr -> sy storage row r+dr
            // y rel cols cg*4-1 .. cg*4+4 -> storage cols cg*4 .. cg*4+5
            const float* rp = &sy[r + dr][cg * 4];
            float4 a  = *(const float4*)(rp);
            float4 bb = *(const float4*)(rp + 4);
            float y0 = a.x, y1 = a.y, y2 = a.z, y3 = a.w, y4 = bb.x, y5 = bb.y;
            float ka = k2[dr * 3 + 0], kb = k2[dr * 3 + 1], kc = k2[dr * 3 + 2];
            s0 += ka * y0 + kb * y1 + kc * y2;
            s1 += ka * y1 + kb * y2 + kc * y3;
            s2 += ka * y2 + kb * y3 + kc * y4;
            s3 += ka * y3 + kb * y4 + kc * y5;
        }
        float4 o = make_float4(s0, s1, s2, s3);
        *(float4*)(ob + (size_t)(row0 + r) * IMG_W + col0 + cg * 4) = o;
    }
}

extern "C" void kernel_launch(void* const* d_in, const int* in_sizes, int n_in,
                              void* d_out, int out_size, void* d_ws, size_t ws_size,
                              hipStream_t stream) {
    const float* x  = (const float*)d_in[0];
    const float* w1 = (const float*)d_in[1];
    const float* w2 = (const float*)d_in[2];
    float* out = (float*)d_out;
    int B = in_sizes[0] / (IMG_H * IMG_W);
    dim3 grid(IMG_W / TILE, IMG_H / TILE, B);
    conv3x3x2_fused<<<grid, dim3(256, 1, 1), 0, stream>>>(x, w1, w2, out, B);
}